// Round 1
// baseline (53.850 us; speedup 1.0000x reference)
//
#include <hip/hip_runtime.h>
#include <math.h>

#define NN 4096
#define DD 7
#define HH 8
#define CUT 3.6f
#define JSPLIT 4
#define JCH (NN / JSPLIT)   // 1024 j's per block
#define RB 32               // rows per block

// ---------------- K1: per-row MLP -> s, node{pos, feats} ----------------
__global__ __launch_bounds__(256) void k_mlp(
    const float* __restrict__ x,
    const float* __restrict__ w1, const float* __restrict__ b1,
    const float* __restrict__ w2, const float* __restrict__ b2,
    const float* __restrict__ w3, const float* __restrict__ b3,
    float* __restrict__ sArr, float* __restrict__ node)
{
    int n = blockIdx.x * blockDim.x + threadIdx.x;
    if (n >= NN) return;
    float xi[DD];
#pragma unroll
    for (int i = 0; i < DD; ++i) xi[i] = x[n * DD + i];

    float h1[HH];
#pragma unroll
    for (int o = 0; o < HH; ++o) {
        float a = b1[o];
#pragma unroll
        for (int i = 0; i < DD; ++i) a = fmaf(xi[i], w1[i * HH + o], a);
        h1[o] = atanf(a);
    }
    float h2[HH];
#pragma unroll
    for (int o = 0; o < HH; ++o) {
        float a = b2[o];
#pragma unroll
        for (int i = 0; i < HH; ++i) a = fmaf(h1[i], w2[i * HH + o], a);
        h2[o] = atanf(a);
    }
    float m[23];
#pragma unroll
    for (int c = 0; c < 23; ++c) {
        float a = b3[c];
#pragma unroll
        for (int i = 0; i < HH; ++i) a = fmaf(h2[i], w3[i * 23 + c], a);
        m[c] = a;
    }
    float s = 0.f;
#pragma unroll
    for (int k = 0; k < 8; ++k) s = fmaf(m[15 + k], m[7 + k], s);
    sArr[n] = s;

    float* nd = node + n * 12;
    nd[0] = xi[0]; nd[1] = xi[1]; nd[2] = xi[2];
    nd[3] = 0.f;                       // e placeholder
#pragma unroll
    for (int d = 0; d < DD; ++d) nd[4 + d] = m[d];   // feats (unscaled)
    nd[11] = 0.f;
}

// ---------------- K2: global max of s ----------------
__global__ __launch_bounds__(1024) void k_max(const float* __restrict__ sArr,
                                              float* __restrict__ gmax)
{
    __shared__ float red[1024];
    int t = threadIdx.x;
    float v = fmaxf(fmaxf(sArr[t], sArr[t + 1024]),
                    fmaxf(sArr[t + 2048], sArr[t + 3072]));
    red[t] = v;
    __syncthreads();
    for (int off = 512; off > 0; off >>= 1) {
        if (t < off) red[t] = fmaxf(red[t], red[t + off]);
        __syncthreads();
    }
    if (t == 0) *gmax = red[0];
}

// ---------------- K3: e = exp(s - gmax); scale feats in node ----------------
__global__ __launch_bounds__(256) void k_pack(const float* __restrict__ sArr,
                                              const float* __restrict__ gmax,
                                              float* __restrict__ node)
{
    int n = blockIdx.x * blockDim.x + threadIdx.x;
    if (n >= NN) return;
    float e = expf(sArr[n] - *gmax);
    float* nd = node + n * 12;
    nd[3] = e;
#pragma unroll
    for (int d = 0; d < DD; ++d) nd[4 + d] *= e;
}

// ---------------- K4: pairwise neighbor-weighted sums per row k ----------------
// part[y][k][ch]: ch 0..6 = sum_j in chunk y, dist<=CUT of e_j*f_j[ch]; ch7 = sum e_j
__global__ __launch_bounds__(256) void k_pair(const float* __restrict__ node,
                                              float* __restrict__ part)
{
    __shared__ float4 tile[JCH * 3];   // 48 KiB
    int xb = blockIdx.x;               // row tile 0..127
    int y  = blockIdx.y;               // j chunk 0..3
    int t  = threadIdx.x;

    const float4* node4 = (const float4*)node;
    int base = y * JCH * 3;
#pragma unroll
    for (int i = t; i < JCH * 3; i += 256) tile[i] = node4[base + i];
    __syncthreads();

    int jl = t & 31;          // j lane
    int rg = t >> 5;          // row group (8 groups of 4 rows)
    int r0 = xb * RB + rg * 4;

    float p[4][3];
#pragma unroll
    for (int rr = 0; rr < 4; ++rr) {
        const float* nd = node + (r0 + rr) * 12;
        p[rr][0] = nd[0]; p[rr][1] = nd[1]; p[rr][2] = nd[2];
    }
    float acc[4][8];
#pragma unroll
    for (int rr = 0; rr < 4; ++rr)
#pragma unroll
        for (int ch = 0; ch < 8; ++ch) acc[rr][ch] = 0.f;

    for (int jj = jl; jj < JCH; jj += 32) {
        float4 a = tile[jj * 3 + 0];   // p0,p1,p2,e
        float4 b = tile[jj * 3 + 1];   // ef0..ef3
        float4 c = tile[jj * 3 + 2];   // ef4,ef5,ef6,pad
#pragma unroll
        for (int rr = 0; rr < 4; ++rr) {
            float dist = fabsf(p[rr][0] - a.x) + fabsf(p[rr][1] - a.y)
                       + fabsf(p[rr][2] - a.z);
            float msel = (dist <= CUT) ? 1.0f : 0.0f;
            acc[rr][0] = fmaf(msel, b.x, acc[rr][0]);
            acc[rr][1] = fmaf(msel, b.y, acc[rr][1]);
            acc[rr][2] = fmaf(msel, b.z, acc[rr][2]);
            acc[rr][3] = fmaf(msel, b.w, acc[rr][3]);
            acc[rr][4] = fmaf(msel, c.x, acc[rr][4]);
            acc[rr][5] = fmaf(msel, c.y, acc[rr][5]);
            acc[rr][6] = fmaf(msel, c.z, acc[rr][6]);
            acc[rr][7] = fmaf(msel, a.w, acc[rr][7]);
        }
    }

    // reduce across the 32 j-lanes (width-32 butterfly)
#pragma unroll
    for (int rr = 0; rr < 4; ++rr)
#pragma unroll
        for (int ch = 0; ch < 8; ++ch) {
            float v = acc[rr][ch];
            v += __shfl_xor(v, 16, 32);
            v += __shfl_xor(v, 8, 32);
            v += __shfl_xor(v, 4, 32);
            v += __shfl_xor(v, 2, 32);
            v += __shfl_xor(v, 1, 32);
            acc[rr][ch] = v;
        }

    if (jl == 0) {
#pragma unroll
        for (int rr = 0; rr < 4; ++rr) {
            float4* pp = (float4*)(part + ((size_t)(y * NN + r0 + rr)) * 8);
            pp[0] = make_float4(acc[rr][0], acc[rr][1], acc[rr][2], acc[rr][3]);
            pp[1] = make_float4(acc[rr][4], acc[rr][5], acc[rr][6], acc[rr][7]);
        }
    }
}

// ---------------- K5: combine 4 partials + inclusive prefix scan over k ----------------
__global__ __launch_bounds__(512) void k_scan(const float* __restrict__ part,
                                              float* __restrict__ prefix)
{
    __shared__ float lds[64][8];
    int t = threadIdx.x;        // 512
    int c = t & 7;              // channel
    int chunk = t >> 3;         // 64 chunks of 64 rows
    const float* p0 = part;
    const float* p1 = part + NN * 8;
    const float* p2 = part + 2 * NN * 8;
    const float* p3 = part + 3 * NN * 8;

    int k0 = chunk * 64;
    float run = 0.f;
    for (int e = 0; e < 64; ++e) {
        int idx = (k0 + e) * 8 + c;
        float v = (p0[idx] + p1[idx]) + (p2[idx] + p3[idx]);
        prefix[idx] = v;        // stash combined value
        run += v;
    }
    lds[chunk][c] = run;
    __syncthreads();
    if (t < 8) {                // serial exclusive scan over 64 chunk-sums
        float r = 0.f;
        for (int ch = 0; ch < 64; ++ch) {
            float tmp = lds[ch][t];
            lds[ch][t] = r;
            r += tmp;
        }
    }
    __syncthreads();
    run = lds[chunk][c];
    for (int e = 0; e < 64; ++e) {
        int idx = (k0 + e) * 8 + c;
        run += prefix[idx];
        prefix[idx] = run;      // inclusive prefix
    }
}

// ---------------- K6: agg = Num/Den; encode + decode ----------------
__global__ __launch_bounds__(256) void k_final(
    const float* __restrict__ x, const float* __restrict__ prefix,
    const float* __restrict__ we, const float* __restrict__ be,
    const float* __restrict__ wd, const float* __restrict__ bd,
    float* __restrict__ out)
{
    int n = blockIdx.x * blockDim.x + threadIdx.x;
    if (n >= NN) return;
    float v[14];
#pragma unroll
    for (int i = 0; i < DD; ++i) v[i] = x[n * DD + i];
    const float* pr = prefix + n * 8;
    float den = pr[7];
#pragma unroll
    for (int d = 0; d < DD; ++d) v[DD + d] = pr[d] / den;

    float codes[HH];
#pragma unroll
    for (int o = 0; o < HH; ++o) {
        float a = be[o];
#pragma unroll
        for (int i = 0; i < 14; ++i) a = fmaf(v[i], we[i * HH + o], a);
        codes[o] = atanf(a);
    }
#pragma unroll
    for (int d = 0; d < DD; ++d) {
        float a = bd[d];
#pragma unroll
        for (int o = 0; o < HH; ++o) a = fmaf(codes[o], wd[o * DD + d], a);
        out[n * DD + d] = a;
    }
}

extern "C" void kernel_launch(void* const* d_in, const int* in_sizes, int n_in,
                              void* d_out, int out_size, void* d_ws, size_t ws_size,
                              hipStream_t stream)
{
    const float* x  = (const float*)d_in[0];
    const float* w1 = (const float*)d_in[1];
    const float* b1 = (const float*)d_in[2];
    const float* w2 = (const float*)d_in[3];
    const float* b2 = (const float*)d_in[4];
    const float* w3 = (const float*)d_in[5];
    const float* b3 = (const float*)d_in[6];
    const float* we = (const float*)d_in[7];
    const float* be = (const float*)d_in[8];
    const float* wd = (const float*)d_in[9];
    const float* bd = (const float*)d_in[10];
    float* out = (float*)d_out;

    float* ws     = (float*)d_ws;
    float* sArr   = ws;                    // 4096
    float* gmax   = ws + NN;               // 1 (+pad 15)
    float* node   = ws + NN + 16;          // 4096*12, 16B aligned
    float* part   = node + NN * 12;        // 4*4096*8
    float* prefix = part + 4 * NN * 8;     // 4096*8
    // total ~868 KB

    k_mlp <<<NN / 256, 256, 0, stream>>>(x, w1, b1, w2, b2, w3, b3, sArr, node);
    k_max <<<1, 1024, 0, stream>>>(sArr, gmax);
    k_pack<<<NN / 256, 256, 0, stream>>>(sArr, gmax, node);
    k_pair<<<dim3(NN / RB, JSPLIT), 256, 0, stream>>>(node, part);
    k_scan<<<1, 512, 0, stream>>>(part, prefix);
    k_final<<<NN / 256, 256, 0, stream>>>(x, prefix, we, be, wd, bd, out);
}

// Round 2
// 29.491 us; speedup vs baseline: 1.8260x; 1.8260x over previous
//
#include <hip/hip_runtime.h>
#include <math.h>

#define NN 4096
#define DD 7
#define HH 8
#define CUT 3.6f
#define JSPLIT 4
#define JCH (NN / JSPLIT)   // 1024 j's per block
#define RB 32               // rows per block

// node layout: 12 floats/row = 3 float4: [p0,p1,p2,s][m0..m3][m4,m5,m6,0]
// part layout: channel-major part[(y*8+ch)*NN + k]
// prefix layout: channel-major prefix[ch*NN + k]

// ---------------- K1: per-row MLP -> node{pos, s, feats}, per-block max ----------------
__global__ __launch_bounds__(256) void k_mlp(
    const float* __restrict__ x,
    const float* __restrict__ w1, const float* __restrict__ b1,
    const float* __restrict__ w2, const float* __restrict__ b2,
    const float* __restrict__ w3, const float* __restrict__ b3,
    float* __restrict__ node, float* __restrict__ bmax)
{
    int t = threadIdx.x;
    int n = blockIdx.x * 256 + t;
    float xi[DD];
#pragma unroll
    for (int i = 0; i < DD; ++i) xi[i] = x[n * DD + i];

    float h1[HH];
#pragma unroll
    for (int o = 0; o < HH; ++o) {
        float a = b1[o];
#pragma unroll
        for (int i = 0; i < DD; ++i) a = fmaf(xi[i], w1[i * HH + o], a);
        h1[o] = atanf(a);
    }
    float h2[HH];
#pragma unroll
    for (int o = 0; o < HH; ++o) {
        float a = b2[o];
#pragma unroll
        for (int i = 0; i < HH; ++i) a = fmaf(h1[i], w2[i * HH + o], a);
        h2[o] = atanf(a);
    }
    float m[23];
#pragma unroll
    for (int c = 0; c < 23; ++c) {
        float a = b3[c];
#pragma unroll
        for (int i = 0; i < HH; ++i) a = fmaf(h2[i], w3[i * 23 + c], a);
        m[c] = a;
    }
    float s = 0.f;
#pragma unroll
    for (int k = 0; k < 8; ++k) s = fmaf(m[15 + k], m[7 + k], s);

    float4* nd4 = (float4*)(node + n * 12);
    nd4[0] = make_float4(xi[0], xi[1], xi[2], s);
    nd4[1] = make_float4(m[0], m[1], m[2], m[3]);
    nd4[2] = make_float4(m[4], m[5], m[6], 0.f);

    // block max of s -> bmax[blockIdx.x]
    float v = s;
#pragma unroll
    for (int off = 32; off > 0; off >>= 1) v = fmaxf(v, __shfl_xor(v, off, 64));
    __shared__ float wm[4];
    if ((t & 63) == 0) wm[t >> 6] = v;
    __syncthreads();
    if (t == 0)
        bmax[blockIdx.x] = fmaxf(fmaxf(wm[0], wm[1]), fmaxf(wm[2], wm[3]));
}

// ---------------- K2: pairwise neighbor-weighted sums per row k ----------------
__global__ __launch_bounds__(256) void k_pair(const float* __restrict__ node,
                                              const float* __restrict__ bmax,
                                              float* __restrict__ part)
{
    __shared__ float4 tile[JCH * 3];   // 48 KiB
    int xb = blockIdx.x;               // row tile 0..127
    int y  = blockIdx.y;               // j chunk 0..3
    int t  = threadIdx.x;

    float gm = bmax[0];
#pragma unroll
    for (int i = 1; i < 16; ++i) gm = fmaxf(gm, bmax[i]);

    // stage chunk y: compute e = exp(s - gmax), scale feats
    const float4* node4 = (const float4*)node;
    int base = y * JCH * 3;
#pragma unroll
    for (int q = 0; q < 4; ++q) {
        int j = q * 256 + t;           // node within chunk
        float4 a = node4[base + j * 3 + 0];
        float4 b = node4[base + j * 3 + 1];
        float4 c = node4[base + j * 3 + 2];
        float e = expf(a.w - gm);
        tile[j * 3 + 0] = make_float4(a.x, a.y, a.z, e);
        tile[j * 3 + 1] = make_float4(e * b.x, e * b.y, e * b.z, e * b.w);
        tile[j * 3 + 2] = make_float4(e * c.x, e * c.y, e * c.z, 0.f);
    }
    __syncthreads();

    int jl = t & 31;          // j lane
    int rg = t >> 5;          // row group (8 groups of 4 rows)
    int r0 = xb * RB + rg * 4;

    float p[4][3];
#pragma unroll
    for (int rr = 0; rr < 4; ++rr) {
        const float* nd = node + (r0 + rr) * 12;
        p[rr][0] = nd[0]; p[rr][1] = nd[1]; p[rr][2] = nd[2];
    }
    float acc[4][8];
#pragma unroll
    for (int rr = 0; rr < 4; ++rr)
#pragma unroll
        for (int ch = 0; ch < 8; ++ch) acc[rr][ch] = 0.f;

    for (int jj = jl; jj < JCH; jj += 32) {
        float4 a = tile[jj * 3 + 0];   // p0,p1,p2,e
        float4 b = tile[jj * 3 + 1];   // ef0..ef3
        float4 c = tile[jj * 3 + 2];   // ef4,ef5,ef6,pad
#pragma unroll
        for (int rr = 0; rr < 4; ++rr) {
            float dist = fabsf(p[rr][0] - a.x) + fabsf(p[rr][1] - a.y)
                       + fabsf(p[rr][2] - a.z);
            float msel = (dist <= CUT) ? 1.0f : 0.0f;
            acc[rr][0] = fmaf(msel, b.x, acc[rr][0]);
            acc[rr][1] = fmaf(msel, b.y, acc[rr][1]);
            acc[rr][2] = fmaf(msel, b.z, acc[rr][2]);
            acc[rr][3] = fmaf(msel, b.w, acc[rr][3]);
            acc[rr][4] = fmaf(msel, c.x, acc[rr][4]);
            acc[rr][5] = fmaf(msel, c.y, acc[rr][5]);
            acc[rr][6] = fmaf(msel, c.z, acc[rr][6]);
            acc[rr][7] = fmaf(msel, a.w, acc[rr][7]);
        }
    }

    // reduce across the 32 j-lanes (width-32 butterfly)
#pragma unroll
    for (int rr = 0; rr < 4; ++rr)
#pragma unroll
        for (int ch = 0; ch < 8; ++ch) {
            float v = acc[rr][ch];
            v += __shfl_xor(v, 16, 32);
            v += __shfl_xor(v, 8, 32);
            v += __shfl_xor(v, 4, 32);
            v += __shfl_xor(v, 2, 32);
            v += __shfl_xor(v, 1, 32);
            acc[rr][ch] = v;
        }

    if (jl == 0) {
#pragma unroll
        for (int rr = 0; rr < 4; ++rr) {
#pragma unroll
            for (int ch = 0; ch < 8; ++ch)
                part[(size_t)(y * 8 + ch) * NN + (r0 + rr)] = acc[rr][ch];
        }
    }
}

// ---------------- K3: combine 4 partials + inclusive prefix scan (per channel) ----------------
__global__ __launch_bounds__(256) void k_scan(const float* __restrict__ part,
                                              float* __restrict__ prefix)
{
    int c = blockIdx.x;        // channel 0..7
    int t = threadIdx.x;       // 256 threads, 16 rows each

    const float4* p0 = (const float4*)(part + (size_t)(0 * 8 + c) * NN);
    const float4* p1 = (const float4*)(part + (size_t)(1 * 8 + c) * NN);
    const float4* p2 = (const float4*)(part + (size_t)(2 * 8 + c) * NN);
    const float4* p3 = (const float4*)(part + (size_t)(3 * 8 + c) * NN);

    float vals[16];
#pragma unroll
    for (int q = 0; q < 4; ++q) {
        int i4 = t * 4 + q;    // float4 index: rows t*16+q*4 .. +3
        float4 a = p0[i4], b = p1[i4], cc = p2[i4], d = p3[i4];
        vals[q * 4 + 0] = (a.x + b.x) + (cc.x + d.x);
        vals[q * 4 + 1] = (a.y + b.y) + (cc.y + d.y);
        vals[q * 4 + 2] = (a.z + b.z) + (cc.z + d.z);
        vals[q * 4 + 3] = (a.w + b.w) + (cc.w + d.w);
    }
    float ts = 0.f;
#pragma unroll
    for (int e = 0; e < 16; ++e) ts += vals[e];

    // inclusive scan of thread sums across 256 threads
    int lane = t & 63, wv = t >> 6;
    float v = ts;
#pragma unroll
    for (int off = 1; off < 64; off <<= 1) {
        float o = __shfl_up(v, off, 64);
        if (lane >= off) v += o;
    }
    __shared__ float wtot[4];
    if (lane == 63) wtot[wv] = v;
    __syncthreads();
    float woff = 0.f;
    for (int w = 0; w < 4; ++w) if (w < wv) woff += wtot[w];
    float run = woff + v - ts;   // exclusive prefix for this thread

    float pr[16];
#pragma unroll
    for (int e = 0; e < 16; ++e) { run += vals[e]; pr[e] = run; }
    float4* out4 = (float4*)(prefix + (size_t)c * NN + t * 16);
#pragma unroll
    for (int q = 0; q < 4; ++q)
        out4[q] = make_float4(pr[q * 4 + 0], pr[q * 4 + 1], pr[q * 4 + 2], pr[q * 4 + 3]);
}

// ---------------- K4: agg = Num/Den; encode + decode ----------------
__global__ __launch_bounds__(256) void k_final(
    const float* __restrict__ x, const float* __restrict__ prefix,
    const float* __restrict__ we, const float* __restrict__ be,
    const float* __restrict__ wd, const float* __restrict__ bd,
    float* __restrict__ out)
{
    int n = blockIdx.x * 256 + threadIdx.x;
    float v[14];
#pragma unroll
    for (int i = 0; i < DD; ++i) v[i] = x[n * DD + i];
    float den = prefix[(size_t)7 * NN + n];
#pragma unroll
    for (int d = 0; d < DD; ++d) v[DD + d] = prefix[(size_t)d * NN + n] / den;

    float codes[HH];
#pragma unroll
    for (int o = 0; o < HH; ++o) {
        float a = be[o];
#pragma unroll
        for (int i = 0; i < 14; ++i) a = fmaf(v[i], we[i * HH + o], a);
        codes[o] = atanf(a);
    }
#pragma unroll
    for (int d = 0; d < DD; ++d) {
        float a = bd[d];
#pragma unroll
        for (int o = 0; o < HH; ++o) a = fmaf(codes[o], wd[o * DD + d], a);
        out[n * DD + d] = a;
    }
}

extern "C" void kernel_launch(void* const* d_in, const int* in_sizes, int n_in,
                              void* d_out, int out_size, void* d_ws, size_t ws_size,
                              hipStream_t stream)
{
    const float* x  = (const float*)d_in[0];
    const float* w1 = (const float*)d_in[1];
    const float* b1 = (const float*)d_in[2];
    const float* w2 = (const float*)d_in[3];
    const float* b2 = (const float*)d_in[4];
    const float* w3 = (const float*)d_in[5];
    const float* b3 = (const float*)d_in[6];
    const float* we = (const float*)d_in[7];
    const float* be = (const float*)d_in[8];
    const float* wd = (const float*)d_in[9];
    const float* bd = (const float*)d_in[10];
    float* out = (float*)d_out;

    float* ws     = (float*)d_ws;
    float* node   = ws;                    // 4096*12 floats (16B aligned)
    float* part   = node + NN * 12;        // 4*8*4096
    float* prefix = part + 4 * 8 * NN;     // 8*4096
    float* bmax   = prefix + 8 * NN;       // 16

    k_mlp  <<<NN / 256, 256, 0, stream>>>(x, w1, b1, w2, b2, w3, b3, node, bmax);
    k_pair <<<dim3(NN / RB, JSPLIT), 256, 0, stream>>>(node, bmax, part);
    k_scan <<<8, 256, 0, stream>>>(part, prefix);
    k_final<<<NN / 256, 256, 0, stream>>>(x, prefix, we, be, wd, bd, out);
}